// Round 9
// baseline (279.854 us; speedup 1.0000x reference)
//
#include <hip/hip_runtime.h>
#include <hip/hip_bf16.h>

#define T_SEQ 1024
#define D_MODEL 512
#define N_HEADS 8
#define D_HEAD 64
// 0.125 (1/sqrt(64)) * log2(e): scores computed directly in exp2 domain
#define KSCALE 0.1803368801111244f

typedef unsigned short ushort_t;
typedef short s16x8 __attribute__((ext_vector_type(8)));
typedef float f32x4 __attribute__((ext_vector_type(4)));

__device__ inline f32x4 mfma16(s16x8 a, s16x8 b, f32x4 c) {
    return __builtin_amdgcn_mfma_f32_16x16x32_bf16(a, b, c, 0, 0, 0);
}

__device__ inline ushort_t f2bf(float f) {   // RTNE float->bf16
    union { float f; unsigned u; } v; v.f = f;
    unsigned r = v.u + 0x7FFFu + ((v.u >> 16) & 1u);
    return (ushort_t)(r >> 16);
}
__device__ inline void cvt4(const float4 f, ushort_t* t) {
    t[0] = f2bf(f.x); t[1] = f2bf(f.y); t[2] = f2bf(f.z); t[3] = f2bf(f.w);
}
__device__ inline s16x8 pack8(const ushort_t* t) {
    s16x8 r;
    #pragma unroll
    for (int e = 0; e < 8; ++e) r[e] = (short)t[e];
    return r;
}

// HBM -> LDS direct DMA, 16 B per lane. lds ptr must be wave-uniform
// (HW writes base + lane*16); global ptr is per-lane.
__device__ inline void gl_lds16(const ushort_t* g, ushort_t* l) {
    __builtin_amdgcn_global_load_lds(
        (const __attribute__((address_space(1))) unsigned*)g,
        (__attribute__((address_space(3))) unsigned*)l, 16, 0, 0);
}

// ---------------------------------------------------------------------------
// prep: blocks [0,2560) cast x->xb + pos->posb (row 2047 zeroed);
//       blocks [2560,2880) transpose+cast the 5 weight matrices into WT.
// ---------------------------------------------------------------------------
__global__ __launch_bounds__(256) void prep(
    const float* __restrict__ x, const float* __restrict__ pos,
    const float* __restrict__ W0, const float* __restrict__ W1,
    const float* __restrict__ W2, const float* __restrict__ W3,
    const float* __restrict__ W4,
    ushort_t* __restrict__ xb, ushort_t* __restrict__ posb,
    ushort_t* __restrict__ WT)
{
    __shared__ float T[64][68];
    const int bx = blockIdx.x;
    const int tid = threadIdx.x;
    if (bx < 2560) {
        const size_t N1 = (size_t)8192 * 512;
        size_t e = ((size_t)bx * 256 + tid) * 8;
        ushort_t tmp[8];
        if (e < N1) {
            const float4* s = (const float4*)(x + e);
            cvt4(s[0], tmp); cvt4(s[1], tmp + 4);
            *(s16x8*)(xb + e) = pack8(tmp);
        } else {
            size_t e2 = e - N1;                 // < 2048*512
            int row = (int)(e2 >> 9);
            if (row < 2047) {
                const float4* s = (const float4*)(pos + e2);
                cvt4(s[0], tmp); cvt4(s[1], tmp + 4);
            } else {
                #pragma unroll
                for (int i = 0; i < 8; ++i) tmp[i] = 0;
            }
            *(s16x8*)(posb + e2) = pack8(tmp);
        }
    } else {
        const int bz = bx - 2560;               // 0..319
        const int z = bz >> 6;                  // 0..4
        const int rem = bz & 63;
        const int n0 = (rem & 7) * 64, k0 = (rem >> 3) * 64;
        const float* W = (z == 0) ? W0 : (z == 1) ? W1
                       : (z == 2) ? W2 : (z == 3) ? W3 : W4;
        const int rr = tid >> 2, cc = (tid & 3) * 16;

        const float* src = W + (size_t)(k0 + rr) * 512 + n0 + cc;
        *(float4*)&T[rr][cc + 0]  = *(const float4*)(src);
        *(float4*)&T[rr][cc + 4]  = *(const float4*)(src + 4);
        *(float4*)&T[rr][cc + 8]  = *(const float4*)(src + 8);
        *(float4*)&T[rr][cc + 12] = *(const float4*)(src + 12);
        __syncthreads();

        ushort_t tmp[16];
        #pragma unroll
        for (int e = 0; e < 16; ++e) tmp[e] = f2bf(T[cc + e][rr]);
        ushort_t* dst = WT + ((size_t)z * 512 + n0 + rr) * 512 + k0 + cc;
        *(s16x8*)dst       = pack8(tmp);
        *(s16x8*)(dst + 8) = pack8(tmp + 8);
    }
}

// ---------------------------------------------------------------------------
// Fused QKV + P GEMM, 128x128 tiles, 4 waves, K=512, global_load_lds staging
// (unpadded [128][64] LDS tiles, m97 pattern; 8 chunks of 16B per row).
// Grid (13, 64): bx<12 -> qkv (set=col0>>9); bx==12 -> P GEMM.
// ---------------------------------------------------------------------------
__global__ __launch_bounds__(256) void gemm_qkvp(
    const ushort_t* __restrict__ xb, const ushort_t* __restrict__ posb,
    const ushort_t* __restrict__ WT,
    const float* __restrict__ bq, const float* __restrict__ bk,
    const float* __restrict__ bv,
    const float* __restrict__ pbu, const float* __restrict__ pbv,
    ushort_t* __restrict__ Qu, ushort_t* __restrict__ Qv,
    ushort_t* __restrict__ Ko, ushort_t* __restrict__ VoT,
    ushort_t* __restrict__ Po)
{
    const int tid = threadIdx.x;
    const bool is_p = (blockIdx.x == 12);
    int row0, col0;
    const ushort_t* A;
    const ushort_t* B;
    if (is_p) {
        row0 = ((int)blockIdx.y >> 2) * 128;     // 0..1920
        col0 = ((int)blockIdx.y & 3) * 128;      // 0..384
        A = posb;
        B = WT + (size_t)3 * 512 * 512;
    } else {
        row0 = blockIdx.y * 128;
        col0 = blockIdx.x * 128;
        A = xb;
        B = WT;                                  // col0 spans 0..1535 across sets
    }
    const int w = tid >> 6, lane = tid & 63;
    const int quad = lane >> 4, lanelo = lane & 15;
    const int wr = w >> 1, wc = w & 1;

    __shared__ ushort_t AsF[128 * 64];           // 16 KB, unpadded (DMA dest)
    __shared__ ushort_t BsF[128 * 64];           // 16 KB

    f32x4 acc[4][4] = {};

    for (int k0 = 0; k0 < 512; k0 += 64) {
        __syncthreads();
        #pragma unroll
        for (int i = 0; i < 4; ++i) {
            const int L = i * 256 + tid;         // 16B-chunk id, 0..1023
            const int r = L >> 3, j = (L & 7) * 8;   // 8 chunks per 64-ushort row
            ushort_t* lbase = AsF + (size_t)(i * 256 + (tid & ~63)) * 8;  // wave-uniform
            gl_lds16(A + (size_t)(row0 + r) * 512 + k0 + j, lbase);
            ushort_t* lbase2 = BsF + (size_t)(i * 256 + (tid & ~63)) * 8;
            gl_lds16(B + (size_t)(col0 + r) * 512 + k0 + j, lbase2);
        }
        __syncthreads();                         // drains vmcnt before barrier

        #pragma unroll
        for (int ks = 0; ks < 2; ++ks) {
            s16x8 af[4], bf[4];
            #pragma unroll
            for (int i = 0; i < 4; ++i)
                af[i] = *(const s16x8*)(AsF + (size_t)(64 * wr + 16 * i + lanelo) * 64 + ks * 32 + quad * 8);
            #pragma unroll
            for (int j = 0; j < 4; ++j)
                bf[j] = *(const s16x8*)(BsF + (size_t)(64 * wc + 16 * j + lanelo) * 64 + ks * 32 + quad * 8);
            #pragma unroll
            for (int i = 0; i < 4; ++i)
                #pragma unroll
                for (int j = 0; j < 4; ++j)
                    acc[i][j] = mfma16(af[i], bf[j], acc[i][j]);
        }
    }

    if (is_p) {
        #pragma unroll
        for (int j = 0; j < 4; ++j) {
            int c = col0 + 64 * wc + 16 * j + lanelo;
            #pragma unroll
            for (int i = 0; i < 4; ++i)
                #pragma unroll
                for (int r = 0; r < 4; ++r) {
                    int row = row0 + 64 * wr + 16 * i + 4 * quad + r;
                    Po[(size_t)row * 512 + c] = f2bf(acc[i][j][r]);
                }
        }
        return;
    }

    const int set = col0 >> 9;               // 0=Q,1=K,2=V (tile never straddles)
    const int cbase = (col0 & 511) + 64 * wc;
    if (set == 0) {
        #pragma unroll
        for (int j = 0; j < 4; ++j) {
            int c = cbase + 16 * j + lanelo;
            float vbq = bq[c], vu = pbu[c], vv = pbv[c];
            #pragma unroll
            for (int i = 0; i < 4; ++i)
                #pragma unroll
                for (int r = 0; r < 4; ++r) {
                    int row = row0 + 64 * wr + 16 * i + 4 * quad + r;
                    size_t o = (size_t)row * 512 + c;
                    float aq = acc[i][j][r] + vbq;
                    Qu[o] = f2bf((aq + vu) * KSCALE);
                    Qv[o] = f2bf((aq + vv) * KSCALE);
                }
        }
    } else if (set == 1) {
        #pragma unroll
        for (int j = 0; j < 4; ++j) {
            int c = cbase + 16 * j + lanelo;
            float vbk = bk[c];
            #pragma unroll
            for (int i = 0; i < 4; ++i)
                #pragma unroll
                for (int r = 0; r < 4; ++r) {
                    int row = row0 + 64 * wr + 16 * i + 4 * quad + r;
                    Ko[(size_t)row * 512 + c] = f2bf(acc[i][j][r] + vbk);
                }
        }
    } else {
        const int b_idx = row0 >> 10;
        #pragma unroll
        for (int j = 0; j < 4; ++j) {
            int c = cbase + 16 * j + lanelo;
            int hh = c >> 6, d = c & 63;
            float vbb = bv[c];
            #pragma unroll
            for (int i = 0; i < 4; ++i) {
                int t = (row0 & 1023) + 64 * wr + 16 * i + 4 * quad;
                ushort4 vp;
                vp.x = f2bf(acc[i][j][0] + vbb);
                vp.y = f2bf(acc[i][j][1] + vbb);
                vp.z = f2bf(acc[i][j][2] + vbb);
                vp.w = f2bf(acc[i][j][3] + vbb);
                *(ushort4*)(VoT + ((size_t)((b_idx * 8 + hh) * 64 + d)) * 1024 + t) = vp;
            }
        }
    }
}

// ---------------------------------------------------------------------------
// MFMA flash attention: fused relative shift (banded, register shuffle
// extraction — 20 shuffles/iter), no-max exp2 softmax, coalesced LDS staging,
// circular 128-slot P window, register-prefetch pipeline.
// Block: (64 q-rows, h, b); wave w owns rows [16w,16w+16).
// ---------------------------------------------------------------------------
__global__ __launch_bounds__(256) void attn_mfma(
    const ushort_t* __restrict__ Qu, const ushort_t* __restrict__ Qv,
    const ushort_t* __restrict__ Kb, const ushort_t* __restrict__ VT,
    const ushort_t* __restrict__ Pb,
    ushort_t* __restrict__ AOb)
{
    const int tid = threadIdx.x;
    const int t0 = blockIdx.x * 64;
    const int h  = blockIdx.y;
    const int b  = blockIdx.z;
    const int w = tid >> 6, lane = tid & 63;
    const int quad = lane >> 4, lanelo = lane & 15;
    const int sr = tid >> 2, sc = (tid & 3) * 16;

    __shared__ ushort_t Kt[64][72];     //  9216 B  [s][d]
    __shared__ ushort_t VtT[64][72];    //  9216 B  [d][s]
    __shared__ ushort_t Pt[128][72];    // 18432 B  circular, slot = row & 127
    __shared__ ushort_t Ps[64][72];     //  9216 B  probs / O staging -> 46080 B

    const size_t qrow = (size_t)(b * T_SEQ + t0 + 16 * w + lanelo) * 512 + h * 64;
    s16x8 qu[2], qv[2];
    qu[0] = *(const s16x8*)(Qu + qrow + quad * 8);
    qu[1] = *(const s16x8*)(Qu + qrow + 32 + quad * 8);
    qv[0] = *(const s16x8*)(Qv + qrow + quad * 8);
    qv[1] = *(const s16x8*)(Qv + qrow + 32 + quad * 8);

    f32x4 acc_o[4] = {};
    float l_part[4] = {0.f, 0.f, 0.f, 0.f};

    const int u_base = lanelo + 63 - 4 * quad;       // u = u_base - r in [48,78]
    const ushort_t* VTbh = VT + ((size_t)((b * 8 + h) * 64)) * 1024;
    const ushort_t* Kbh  = Kb + (size_t)b * T_SEQ * 512 + (size_t)h * 64;
    const int pr_base = 960 - t0;                    // window start at s0=0

    // ---- prologue: stage iter-0 K, V^T, and full 128-row P window ----
    {
        const ushort_t* kp = Kbh + (size_t)sr * 512 + sc;
        *(s16x8*)&Kt[sr][sc]     = *(const s16x8*)kp;
        *(s16x8*)&Kt[sr][sc + 8] = *(const s16x8*)(kp + 8);
        const ushort_t* vp = VTbh + (size_t)sr * 1024 + sc;
        *(s16x8*)&VtT[sr][sc]     = *(const s16x8*)vp;
        *(s16x8*)&VtT[sr][sc + 8] = *(const s16x8*)(vp + 8);
        const int pr_r = tid >> 1, pr_c = (tid & 1) * 32;
        const int slot = (pr_base + pr_r) & 127;
        const ushort_t* gp = Pb + (size_t)(pr_base + pr_r) * 512 + h * 64 + pr_c;
        *(s16x8*)&Pt[slot][pr_c +  0] = *(const s16x8*)(gp +  0);
        *(s16x8*)&Pt[slot][pr_c +  8] = *(const s16x8*)(gp +  8);
        *(s16x8*)&Pt[slot][pr_c + 16] = *(const s16x8*)(gp + 16);
        *(s16x8*)&Pt[slot][pr_c + 24] = *(const s16x8*)(gp + 24);
    }

    for (int it = 0; it < 16; ++it) {
        const int s0 = it * 64;
        __syncthreads();                 // staged data visible

        // ---- prefetch next iter into registers (VMEM overlaps compute) ----
        s16x8 kp0, kp1, vp0, vp1, pp0, pp1;
        const bool more = (it < 15);
        if (more) {
            const ushort_t* kp = Kbh + (size_t)(s0 + 64 + sr) * 512 + sc;
            kp0 = *(const s16x8*)kp;
            kp1 = *(const s16x8*)(kp + 8);
            const ushort_t* vp = VTbh + (size_t)sr * 1024 + s0 + 64 + sc;
            vp0 = *(const s16x8*)vp;
            vp1 = *(const s16x8*)(vp + 8);
            const ushort_t* gp = Pb + (size_t)(pr_base + s0 + 128 + sr) * 512 + h * 64 + sc;
            pp0 = *(const s16x8*)gp;
            pp1 = *(const s16x8*)(gp + 8);
        }

        // ---- compute ----
        const int pbase = (pr_base + s0) & 127;
        f32x4 acc_c[4] = {};
        f32x4 acc_g[5] = {};
        #pragma unroll
        for (int ks = 0; ks < 2; ++ks) {
            #pragma unroll
            for (int tn = 0; tn < 4; ++tn) {
                s16x8 kf = *(const s16x8*)&Kt[tn * 16 + lanelo][ks * 32 + quad * 8];
                acc_c[tn] = mfma16(qu[ks], kf, acc_c[tn]);
            }
            #pragma unroll
            for (int i = 0; i < 5; ++i) {      // jt = 3 - w + i
                int prow = (pbase + (3 - w + i) * 16 + lanelo) & 127;
                s16x8 pf = *(const s16x8*)&Pt[prow][ks * 32 + quad * 8];
                acc_g[i] = mfma16(qv[ks], pf, acc_g[i]);
            }
        }

        // band extraction + exp2 (no max subtraction; softmax shift-invariant)
        float p[4][4];
        #pragma unroll
        for (int r = 0; r < 4; ++r) {
            int u = u_base - r;
            int srcl = (quad << 4) | (u & 15);
            bool hi = (u >= 64);
            float gs[5];
            #pragma unroll
            for (int i = 0; i < 5; ++i) gs[i] = __shfl(acc_g[i][r], srcl);
            #pragma unroll
            for (int tn = 0; tn < 4; ++tn) {
                float e = __builtin_amdgcn_exp2f(acc_c[tn][r] + (hi ? gs[tn + 1] : gs[tn]));
                p[tn][r] = e;
                l_part[r] += e;
            }
        }
        #pragma unroll
        for (int tn = 0; tn < 4; ++tn)
            #pragma unroll
            for (int r = 0; r < 4; ++r)
                Ps[16 * w + 4 * quad + r][tn * 16 + lanelo] = f2bf(p[tn][r]);
        asm volatile("s_waitcnt lgkmcnt(0)" ::: "memory");

        // PV: A = probs (wave-private Ps rows), B = V^T tile in LDS
        #pragma unroll
        for (int ks = 0; ks < 2; ++ks) {
            s16x8 af = *(const s16x8*)&Ps[16 * w + lanelo][ks * 32 + quad * 8];
            #pragma unroll
            for (int dt = 0; dt < 4; ++dt) {
                s16x8 vb = *(const s16x8*)&VtT[dt * 16 + lanelo][ks * 32 + quad * 8];
                acc_o[dt] = mfma16(af, vb, acc_o[dt]);
            }
        }

        __syncthreads();                 // compute done before LDS overwrite
        if (more) {
            *(s16x8*)&Kt[sr][sc]      = kp0;
            *(s16x8*)&Kt[sr][sc + 8]  = kp1;
            *(s16x8*)&VtT[sr][sc]     = vp0;
            *(s16x8*)&VtT[sr][sc + 8] = vp1;
            const int slot = (pr_base + s0 + 128 + sr) & 127;
            *(s16x8*)&Pt[slot][sc]     = pp0;
            *(s16x8*)&Pt[slot][sc + 8] = pp1;
        }
    }

    // single end-of-kernel l reduction (16 lanes per row group)
    float inv[4];
    #pragma unroll
    for (int r = 0; r < 4; ++r) {
        float l = l_part[r];
        l += __shfl_xor(l, 1);
        l += __shfl_xor(l, 2);
        l += __shfl_xor(l, 4);
        l += __shfl_xor(l, 8);
        inv[r] = 1.0f / l;
    }

    // epilogue: stage O into Ps (bf16), then coalesced vector stores
    __syncthreads();
    #pragma unroll
    for (int r = 0; r < 4; ++r)
        #pragma unroll
        for (int dt = 0; dt < 4; ++dt)
            Ps[16 * w + 4 * quad + r][dt * 16 + lanelo] = f2bf(acc_o[dt][r] * inv[r]);
    __syncthreads();
    {
        ushort_t* dst = AOb + (size_t)(b * T_SEQ + t0 + sr) * 512 + h * 64 + sc;
        *(s16x8*)dst       = *(const s16x8*)&Ps[sr][sc];
        *(s16x8*)(dst + 8) = *(const s16x8*)&Ps[sr][sc + 8];
    }
}

// ---------------------------------------------------------------------------
// Final projection: out = AOb @ WoT + bo  (A bf16, fp32 out), 128x128 tiles,
// global_load_lds staging.
// ---------------------------------------------------------------------------
__global__ __launch_bounds__(256) void gemm_out(
    const ushort_t* __restrict__ A, const ushort_t* __restrict__ WTo,
    const float* __restrict__ bias, float* __restrict__ C)
{
    const int tid = threadIdx.x;
    const int col0 = blockIdx.x * 128;
    const int row0 = blockIdx.y * 128;
    const int w = tid >> 6, lane = tid & 63;
    const int quad = lane >> 4, lanelo = lane & 15;
    const int wr = w >> 1, wc = w & 1;

    __shared__ ushort_t AsF[128 * 64];
    __shared__ ushort_t BsF[128 * 64];

    f32x4 acc[4][4] = {};

    for (int k0 = 0; k0 < 512; k0 += 64) {
        __syncthreads();
        #pragma unroll
        for (int i = 0; i < 4; ++i) {
            const int L = i * 256 + tid;
            const int r = L >> 3, j = (L & 7) * 8;   // 8 chunks per 64-ushort row
            ushort_t* lbase = AsF + (size_t)(i * 256 + (tid & ~63)) * 8;
            gl_lds16(A + (size_t)(row0 + r) * 512 + k0 + j, lbase);
            ushort_t* lbase2 = BsF + (size_t)(i * 256 + (tid & ~63)) * 8;
            gl_lds16(WTo + (size_t)(col0 + r) * 512 + k0 + j, lbase2);
        }
        __syncthreads();

        #pragma unroll
        for (int ks = 0; ks < 2; ++ks) {
            s16x8 af[4], bf[4];
            #pragma unroll
            for (int i = 0; i < 4; ++i)
                af[i] = *(const s16x8*)(AsF + (size_t)(64 * wr + 16 * i + lanelo) * 64 + ks * 32 + quad * 8);
            #pragma unroll
            for (int j = 0; j < 4; ++j)
                bf[j] = *(const s16x8*)(BsF + (size_t)(64 * wc + 16 * j + lanelo) * 64 + ks * 32 + quad * 8);
            #pragma unroll
            for (int i = 0; i < 4; ++i)
                #pragma unroll
                for (int j = 0; j < 4; ++j)
                    acc[i][j] = mfma16(af[i], bf[j], acc[i][j]);
        }
    }

    #pragma unroll
    for (int j = 0; j < 4; ++j) {
        int c = col0 + 64 * wc + 16 * j + lanelo;
        float vb = bias[c];
        #pragma unroll
        for (int i = 0; i < 4; ++i)
            #pragma unroll
            for (int r = 0; r < 4; ++r) {
                int row = row0 + 64 * wr + 16 * i + 4 * quad + r;
                C[(size_t)row * 512 + c] = acc[i][j][r] + vb;
            }
    }
}

// ---------------------------------------------------------------------------
extern "C" void kernel_launch(void* const* d_in, const int* in_sizes, int n_in,
                              void* d_out, int out_size, void* d_ws, size_t ws_size,
                              hipStream_t stream) {
    const float* x       = (const float*)d_in[0];
    const float* pos_enc = (const float*)d_in[1];
    const float* Wq      = (const float*)d_in[2];
    const float* bq      = (const float*)d_in[3];
    const float* Wk      = (const float*)d_in[4];
    const float* bk      = (const float*)d_in[5];
    const float* Wv      = (const float*)d_in[6];
    const float* bv      = (const float*)d_in[7];
    const float* Wpos    = (const float*)d_in[8];
    const float* pbu     = (const float*)d_in[9];
    const float* pbv     = (const float*)d_in[10];
    const float* Wo      = (const float*)d_in[11];
    const float* bo      = (const float*)d_in[12];
    float* out = (float*)d_out;

    const size_t M  = 8 * T_SEQ;                 // 8192
    const size_t SZ = M * D_MODEL;               // 4,194,304

    char* ws = (char*)d_ws;
    ushort_t* xb   = (ushort_t*)ws;              ws += SZ * 2;
    ushort_t* posb = (ushort_t*)ws;              ws += (size_t)2048 * 512 * 2;
    ushort_t* Qu_b = (ushort_t*)ws;              ws += SZ * 2;
    ushort_t* Qv_b = (ushort_t*)ws;              ws += SZ * 2;
    ushort_t* K_b  = (ushort_t*)ws;              ws += SZ * 2;
    ushort_t* VT_b = (ushort_t*)ws;              ws += SZ * 2;
    ushort_t* P_b  = (ushort_t*)ws;              ws += (size_t)2048 * 512 * 2;
    ushort_t* WT   = (ushort_t*)ws;              ws += (size_t)5 * 512 * 512 * 2;
    ushort_t* AOb  = (ushort_t*)ws;              ws += SZ * 2;

    dim3 blk(256);

    hipLaunchKernelGGL(prep, dim3(2880), blk, 0, stream,
                       x, pos_enc, Wq, Wk, Wv, Wpos, Wo, xb, posb, WT);

    hipLaunchKernelGGL(gemm_qkvp, dim3(13, 64), blk, 0, stream,
                       xb, posb, WT, bq, bk, bv, pbu, pbv,
                       Qu_b, Qv_b, K_b, VT_b, P_b);

    hipLaunchKernelGGL(attn_mfma, dim3(16, 8, 8), blk, 0, stream,
                       Qu_b, Qv_b, K_b, VT_b, P_b, AOb);

    hipLaunchKernelGGL(gemm_out, dim3(4, 64), blk, 0, stream,
                       AOb, WT + (size_t)4 * 512 * 512, bo, out);
}

// Round 10
// 230.732 us; speedup vs baseline: 1.2129x; 1.2129x over previous
//
#include <hip/hip_runtime.h>
#include <hip/hip_bf16.h>

#define T_SEQ 1024
#define D_MODEL 512
#define N_HEADS 8
#define D_HEAD 64
// 0.125 (1/sqrt(64)) * log2(e): scores computed directly in exp2 domain
#define KSCALE 0.1803368801111244f

typedef unsigned short ushort_t;
typedef short s16x8 __attribute__((ext_vector_type(8)));
typedef float f32x4 __attribute__((ext_vector_type(4)));

__device__ inline f32x4 mfma16(s16x8 a, s16x8 b, f32x4 c) {
    return __builtin_amdgcn_mfma_f32_16x16x32_bf16(a, b, c, 0, 0, 0);
}

__device__ inline ushort_t f2bf(float f) {   // RTNE float->bf16
    union { float f; unsigned u; } v; v.f = f;
    unsigned r = v.u + 0x7FFFu + ((v.u >> 16) & 1u);
    return (ushort_t)(r >> 16);
}
__device__ inline void cvt4(const float4 f, ushort_t* t) {
    t[0] = f2bf(f.x); t[1] = f2bf(f.y); t[2] = f2bf(f.z); t[3] = f2bf(f.w);
}
__device__ inline s16x8 pack8(const ushort_t* t) {
    s16x8 r;
    #pragma unroll
    for (int e = 0; e < 8; ++e) r[e] = (short)t[e];
    return r;
}

// HBM -> LDS direct DMA, 16 B per lane. lds ptr must be wave-uniform
// (HW writes base + lane*16); global ptr is per-lane.
__device__ inline void gl_lds16(const ushort_t* g, ushort_t* l) {
    __builtin_amdgcn_global_load_lds(
        (const __attribute__((address_space(1))) unsigned*)g,
        (__attribute__((address_space(3))) unsigned*)l, 16, 0, 0);
}

// ---------------------------------------------------------------------------
// prep: blocks [0,2560) cast x->xb + pos->posb (row 2047 zeroed);
//       blocks [2560,2880) transpose+cast the 5 weight matrices into WT.
// ---------------------------------------------------------------------------
__global__ __launch_bounds__(256) void prep(
    const float* __restrict__ x, const float* __restrict__ pos,
    const float* __restrict__ W0, const float* __restrict__ W1,
    const float* __restrict__ W2, const float* __restrict__ W3,
    const float* __restrict__ W4,
    ushort_t* __restrict__ xb, ushort_t* __restrict__ posb,
    ushort_t* __restrict__ WT)
{
    __shared__ float T[64][68];
    const int bx = blockIdx.x;
    const int tid = threadIdx.x;
    if (bx < 2560) {
        const size_t N1 = (size_t)8192 * 512;
        size_t e = ((size_t)bx * 256 + tid) * 8;
        ushort_t tmp[8];
        if (e < N1) {
            const float4* s = (const float4*)(x + e);
            cvt4(s[0], tmp); cvt4(s[1], tmp + 4);
            *(s16x8*)(xb + e) = pack8(tmp);
        } else {
            size_t e2 = e - N1;                 // < 2048*512
            int row = (int)(e2 >> 9);
            if (row < 2047) {
                const float4* s = (const float4*)(pos + e2);
                cvt4(s[0], tmp); cvt4(s[1], tmp + 4);
            } else {
                #pragma unroll
                for (int i = 0; i < 8; ++i) tmp[i] = 0;
            }
            *(s16x8*)(posb + e2) = pack8(tmp);
        }
    } else {
        const int bz = bx - 2560;               // 0..319
        const int z = bz >> 6;                  // 0..4
        const int rem = bz & 63;
        const int n0 = (rem & 7) * 64, k0 = (rem >> 3) * 64;
        const float* W = (z == 0) ? W0 : (z == 1) ? W1
                       : (z == 2) ? W2 : (z == 3) ? W3 : W4;
        const int rr = tid >> 2, cc = (tid & 3) * 16;

        const float* src = W + (size_t)(k0 + rr) * 512 + n0 + cc;
        *(float4*)&T[rr][cc + 0]  = *(const float4*)(src);
        *(float4*)&T[rr][cc + 4]  = *(const float4*)(src + 4);
        *(float4*)&T[rr][cc + 8]  = *(const float4*)(src + 8);
        *(float4*)&T[rr][cc + 12] = *(const float4*)(src + 12);
        __syncthreads();

        ushort_t tmp[16];
        #pragma unroll
        for (int e = 0; e < 16; ++e) tmp[e] = f2bf(T[cc + e][rr]);
        ushort_t* dst = WT + ((size_t)z * 512 + n0 + rr) * 512 + k0 + cc;
        *(s16x8*)dst       = pack8(tmp);
        *(s16x8*)(dst + 8) = pack8(tmp + 8);
    }
}

// ---------------------------------------------------------------------------
// Fused QKV + P GEMM, 128x128 tiles, 4 waves, K=512, global_load_lds staging
// (unpadded [128][64] LDS tiles, m97 pattern; 8 chunks of 16B per row).
// Grid (13, 64): bx<12 -> qkv (set=col0>>9); bx==12 -> P GEMM.
// ---------------------------------------------------------------------------
__global__ __launch_bounds__(256) void gemm_qkvp(
    const ushort_t* __restrict__ xb, const ushort_t* __restrict__ posb,
    const ushort_t* __restrict__ WT,
    const float* __restrict__ bq, const float* __restrict__ bk,
    const float* __restrict__ bv,
    const float* __restrict__ pbu, const float* __restrict__ pbv,
    ushort_t* __restrict__ Qu, ushort_t* __restrict__ Qv,
    ushort_t* __restrict__ Ko, ushort_t* __restrict__ VoT,
    ushort_t* __restrict__ Po)
{
    const int tid = threadIdx.x;
    const bool is_p = (blockIdx.x == 12);
    int row0, col0;
    const ushort_t* A;
    const ushort_t* B;
    if (is_p) {
        row0 = ((int)blockIdx.y >> 2) * 128;     // 0..1920
        col0 = ((int)blockIdx.y & 3) * 128;      // 0..384
        A = posb;
        B = WT + (size_t)3 * 512 * 512;
    } else {
        row0 = blockIdx.y * 128;
        col0 = blockIdx.x * 128;
        A = xb;
        B = WT;                                  // col0 spans 0..1535 across sets
    }
    const int w = tid >> 6, lane = tid & 63;
    const int quad = lane >> 4, lanelo = lane & 15;
    const int wr = w >> 1, wc = w & 1;

    __shared__ ushort_t AsF[128 * 64];           // 16 KB, unpadded (DMA dest)
    __shared__ ushort_t BsF[128 * 64];           // 16 KB

    f32x4 acc[4][4] = {};

    for (int k0 = 0; k0 < 512; k0 += 64) {
        __syncthreads();
        #pragma unroll
        for (int i = 0; i < 4; ++i) {
            const int L = i * 256 + tid;         // 16B-chunk id, 0..1023
            const int r = L >> 3, j = (L & 7) * 8;   // 8 chunks per 64-ushort row
            ushort_t* lbase = AsF + (size_t)(i * 256 + (tid & ~63)) * 8;  // wave-uniform
            gl_lds16(A + (size_t)(row0 + r) * 512 + k0 + j, lbase);
            ushort_t* lbase2 = BsF + (size_t)(i * 256 + (tid & ~63)) * 8;
            gl_lds16(B + (size_t)(col0 + r) * 512 + k0 + j, lbase2);
        }
        __syncthreads();                         // drains vmcnt before barrier

        #pragma unroll
        for (int ks = 0; ks < 2; ++ks) {
            s16x8 af[4], bf[4];
            #pragma unroll
            for (int i = 0; i < 4; ++i)
                af[i] = *(const s16x8*)(AsF + (size_t)(64 * wr + 16 * i + lanelo) * 64 + ks * 32 + quad * 8);
            #pragma unroll
            for (int j = 0; j < 4; ++j)
                bf[j] = *(const s16x8*)(BsF + (size_t)(64 * wc + 16 * j + lanelo) * 64 + ks * 32 + quad * 8);
            #pragma unroll
            for (int i = 0; i < 4; ++i)
                #pragma unroll
                for (int j = 0; j < 4; ++j)
                    acc[i][j] = mfma16(af[i], bf[j], acc[i][j]);
        }
    }

    if (is_p) {
        #pragma unroll
        for (int j = 0; j < 4; ++j) {
            int c = col0 + 64 * wc + 16 * j + lanelo;
            #pragma unroll
            for (int i = 0; i < 4; ++i)
                #pragma unroll
                for (int r = 0; r < 4; ++r) {
                    int row = row0 + 64 * wr + 16 * i + 4 * quad + r;
                    Po[(size_t)row * 512 + c] = f2bf(acc[i][j][r]);
                }
        }
        return;
    }

    const int set = col0 >> 9;               // 0=Q,1=K,2=V (tile never straddles)
    const int cbase = (col0 & 511) + 64 * wc;
    if (set == 0) {
        #pragma unroll
        for (int j = 0; j < 4; ++j) {
            int c = cbase + 16 * j + lanelo;
            float vbq = bq[c], vu = pbu[c], vv = pbv[c];
            #pragma unroll
            for (int i = 0; i < 4; ++i)
                #pragma unroll
                for (int r = 0; r < 4; ++r) {
                    int row = row0 + 64 * wr + 16 * i + 4 * quad + r;
                    size_t o = (size_t)row * 512 + c;
                    float aq = acc[i][j][r] + vbq;
                    Qu[o] = f2bf((aq + vu) * KSCALE);
                    Qv[o] = f2bf((aq + vv) * KSCALE);
                }
        }
    } else if (set == 1) {
        #pragma unroll
        for (int j = 0; j < 4; ++j) {
            int c = cbase + 16 * j + lanelo;
            float vbk = bk[c];
            #pragma unroll
            for (int i = 0; i < 4; ++i)
                #pragma unroll
                for (int r = 0; r < 4; ++r) {
                    int row = row0 + 64 * wr + 16 * i + 4 * quad + r;
                    Ko[(size_t)row * 512 + c] = f2bf(acc[i][j][r] + vbk);
                }
        }
    } else {
        const int b_idx = row0 >> 10;
        #pragma unroll
        for (int j = 0; j < 4; ++j) {
            int c = cbase + 16 * j + lanelo;
            int hh = c >> 6, d = c & 63;
            float vbb = bv[c];
            #pragma unroll
            for (int i = 0; i < 4; ++i) {
                int t = (row0 & 1023) + 64 * wr + 16 * i + 4 * quad;
                ushort4 vp;
                vp.x = f2bf(acc[i][j][0] + vbb);
                vp.y = f2bf(acc[i][j][1] + vbb);
                vp.z = f2bf(acc[i][j][2] + vbb);
                vp.w = f2bf(acc[i][j][3] + vbb);
                *(ushort4*)(VoT + ((size_t)((b_idx * 8 + hh) * 64 + d)) * 1024 + t) = vp;
            }
        }
    }
}

// ---------------------------------------------------------------------------
// MFMA flash attention (round-7 body, verbatim): fused relative shift
// (banded, inline v0/v1 register shuffle extraction — NO private arrays:
// a float gs[5] here gets PromoteAlloca'd to LDS, +5KB and a 63% regression),
// no-max exp2 softmax, coalesced LDS staging, circular 128-slot P window,
// register-prefetch pipeline. Block: (64 q-rows, h, b); wave w rows [16w,+16).
// ---------------------------------------------------------------------------
__global__ __launch_bounds__(256) void attn_mfma(
    const ushort_t* __restrict__ Qu, const ushort_t* __restrict__ Qv,
    const ushort_t* __restrict__ Kb, const ushort_t* __restrict__ VT,
    const ushort_t* __restrict__ Pb,
    ushort_t* __restrict__ AOb)
{
    const int tid = threadIdx.x;
    const int t0 = blockIdx.x * 64;
    const int h  = blockIdx.y;
    const int b  = blockIdx.z;
    const int w = tid >> 6, lane = tid & 63;
    const int quad = lane >> 4, lanelo = lane & 15;
    const int sr = tid >> 2, sc = (tid & 3) * 16;

    __shared__ ushort_t Kt[64][72];     //  9216 B  [s][d]
    __shared__ ushort_t VtT[64][72];    //  9216 B  [d][s]
    __shared__ ushort_t Pt[128][72];    // 18432 B  circular, slot = row & 127
    __shared__ ushort_t Ps[64][72];     //  9216 B  probs / O staging -> 46080 B

    const size_t qrow = (size_t)(b * T_SEQ + t0 + 16 * w + lanelo) * 512 + h * 64;
    s16x8 qu[2], qv[2];
    qu[0] = *(const s16x8*)(Qu + qrow + quad * 8);
    qu[1] = *(const s16x8*)(Qu + qrow + 32 + quad * 8);
    qv[0] = *(const s16x8*)(Qv + qrow + quad * 8);
    qv[1] = *(const s16x8*)(Qv + qrow + 32 + quad * 8);

    f32x4 acc_o[4] = {};
    float l_part[4] = {0.f, 0.f, 0.f, 0.f};

    const int u_base = lanelo + 63 - 4 * quad;       // u = u_base - r in [48,78]
    const ushort_t* VTbh = VT + ((size_t)((b * 8 + h) * 64)) * 1024;
    const ushort_t* Kbh  = Kb + (size_t)b * T_SEQ * 512 + (size_t)h * 64;
    const int pr_base = 960 - t0;                    // window start at s0=0

    // ---- prologue: stage iter-0 K, V^T, and full 128-row P window ----
    {
        const ushort_t* kp = Kbh + (size_t)sr * 512 + sc;
        *(s16x8*)&Kt[sr][sc]     = *(const s16x8*)kp;
        *(s16x8*)&Kt[sr][sc + 8] = *(const s16x8*)(kp + 8);
        const ushort_t* vp = VTbh + (size_t)sr * 1024 + sc;
        *(s16x8*)&VtT[sr][sc]     = *(const s16x8*)vp;
        *(s16x8*)&VtT[sr][sc + 8] = *(const s16x8*)(vp + 8);
        const int pr_r = tid >> 1, pr_c = (tid & 1) * 32;
        const int slot = (pr_base + pr_r) & 127;
        const ushort_t* gp = Pb + (size_t)(pr_base + pr_r) * 512 + h * 64 + pr_c;
        *(s16x8*)&Pt[slot][pr_c +  0] = *(const s16x8*)(gp +  0);
        *(s16x8*)&Pt[slot][pr_c +  8] = *(const s16x8*)(gp +  8);
        *(s16x8*)&Pt[slot][pr_c + 16] = *(const s16x8*)(gp + 16);
        *(s16x8*)&Pt[slot][pr_c + 24] = *(const s16x8*)(gp + 24);
    }

    for (int it = 0; it < 16; ++it) {
        const int s0 = it * 64;
        __syncthreads();                 // staged data visible

        // ---- prefetch next iter into registers (VMEM overlaps compute) ----
        s16x8 kp0, kp1, vp0, vp1, pp0, pp1;
        const bool more = (it < 15);
        if (more) {
            const ushort_t* kp = Kbh + (size_t)(s0 + 64 + sr) * 512 + sc;
            kp0 = *(const s16x8*)kp;
            kp1 = *(const s16x8*)(kp + 8);
            const ushort_t* vp = VTbh + (size_t)sr * 1024 + s0 + 64 + sc;
            vp0 = *(const s16x8*)vp;
            vp1 = *(const s16x8*)(vp + 8);
            const ushort_t* gp = Pb + (size_t)(pr_base + s0 + 128 + sr) * 512 + h * 64 + sc;
            pp0 = *(const s16x8*)gp;
            pp1 = *(const s16x8*)(gp + 8);
        }

        // ---- compute ----
        const int pbase = (pr_base + s0) & 127;
        f32x4 acc_c[4] = {};
        f32x4 acc_g[5] = {};
        #pragma unroll
        for (int ks = 0; ks < 2; ++ks) {
            #pragma unroll
            for (int tn = 0; tn < 4; ++tn) {
                s16x8 kf = *(const s16x8*)&Kt[tn * 16 + lanelo][ks * 32 + quad * 8];
                acc_c[tn] = mfma16(qu[ks], kf, acc_c[tn]);
            }
            #pragma unroll
            for (int i = 0; i < 5; ++i) {      // jt = 3 - w + i
                int prow = (pbase + (3 - w + i) * 16 + lanelo) & 127;
                s16x8 pf = *(const s16x8*)&Pt[prow][ks * 32 + quad * 8];
                acc_g[i] = mfma16(qv[ks], pf, acc_g[i]);
            }
        }

        // band extraction + exp2 (no max subtraction; softmax shift-invariant)
        float p[4][4];
        #pragma unroll
        for (int r = 0; r < 4; ++r) {
            int u = u_base - r;
            int srcl = (quad << 4) | (u & 15);
            bool hi = (u >= 64);
            #pragma unroll
            for (int tn = 0; tn < 4; ++tn) {
                float v0 = __shfl(acc_g[tn][r], srcl);
                float v1 = __shfl(acc_g[tn + 1][r], srcl);
                float e = __builtin_amdgcn_exp2f(acc_c[tn][r] + (hi ? v1 : v0));
                p[tn][r] = e;
                l_part[r] += e;
            }
        }
        #pragma unroll
        for (int tn = 0; tn < 4; ++tn)
            #pragma unroll
            for (int r = 0; r < 4; ++r)
                Ps[16 * w + 4 * quad + r][tn * 16 + lanelo] = f2bf(p[tn][r]);
        asm volatile("s_waitcnt lgkmcnt(0)" ::: "memory");

        // PV: A = probs (wave-private Ps rows), B = V^T tile in LDS
        #pragma unroll
        for (int ks = 0; ks < 2; ++ks) {
            s16x8 af = *(const s16x8*)&Ps[16 * w + lanelo][ks * 32 + quad * 8];
            #pragma unroll
            for (int dt = 0; dt < 4; ++dt) {
                s16x8 vb = *(const s16x8*)&VtT[dt * 16 + lanelo][ks * 32 + quad * 8];
                acc_o[dt] = mfma16(af, vb, acc_o[dt]);
            }
        }

        __syncthreads();                 // compute done before LDS overwrite
        if (more) {
            *(s16x8*)&Kt[sr][sc]      = kp0;
            *(s16x8*)&Kt[sr][sc + 8]  = kp1;
            *(s16x8*)&VtT[sr][sc]     = vp0;
            *(s16x8*)&VtT[sr][sc + 8] = vp1;
            const int slot = (pr_base + s0 + 128 + sr) & 127;
            *(s16x8*)&Pt[slot][sc]     = pp0;
            *(s16x8*)&Pt[slot][sc + 8] = pp1;
        }
    }

    // single end-of-kernel l reduction (16 lanes per row group)
    float inv[4];
    #pragma unroll
    for (int r = 0; r < 4; ++r) {
        float l = l_part[r];
        l += __shfl_xor(l, 1);
        l += __shfl_xor(l, 2);
        l += __shfl_xor(l, 4);
        l += __shfl_xor(l, 8);
        inv[r] = 1.0f / l;
    }

    // epilogue: stage O into Ps (bf16), then coalesced vector stores
    __syncthreads();
    #pragma unroll
    for (int r = 0; r < 4; ++r)
        #pragma unroll
        for (int dt = 0; dt < 4; ++dt)
            Ps[16 * w + 4 * quad + r][dt * 16 + lanelo] = f2bf(acc_o[dt][r] * inv[r]);
    __syncthreads();
    {
        ushort_t* dst = AOb + (size_t)(b * T_SEQ + t0 + sr) * 512 + h * 64 + sc;
        *(s16x8*)dst       = *(const s16x8*)&Ps[sr][sc];
        *(s16x8*)(dst + 8) = *(const s16x8*)&Ps[sr][sc + 8];
    }
}

// ---------------------------------------------------------------------------
// Final projection: out = AOb @ WoT + bo  (A bf16, fp32 out), 128x128 tiles,
// global_load_lds staging.
// ---------------------------------------------------------------------------
__global__ __launch_bounds__(256) void gemm_out(
    const ushort_t* __restrict__ A, const ushort_t* __restrict__ WTo,
    const float* __restrict__ bias, float* __restrict__ C)
{
    const int tid = threadIdx.x;
    const int col0 = blockIdx.x * 128;
    const int row0 = blockIdx.y * 128;
    const int w = tid >> 6, lane = tid & 63;
    const int quad = lane >> 4, lanelo = lane & 15;
    const int wr = w >> 1, wc = w & 1;

    __shared__ ushort_t AsF[128 * 64];
    __shared__ ushort_t BsF[128 * 64];

    f32x4 acc[4][4] = {};

    for (int k0 = 0; k0 < 512; k0 += 64) {
        __syncthreads();
        #pragma unroll
        for (int i = 0; i < 4; ++i) {
            const int L = i * 256 + tid;
            const int r = L >> 3, j = (L & 7) * 8;   // 8 chunks per 64-ushort row
            ushort_t* lbase = AsF + (size_t)(i * 256 + (tid & ~63)) * 8;
            gl_lds16(A + (size_t)(row0 + r) * 512 + k0 + j, lbase);
            ushort_t* lbase2 = BsF + (size_t)(i * 256 + (tid & ~63)) * 8;
            gl_lds16(WTo + (size_t)(col0 + r) * 512 + k0 + j, lbase2);
        }
        __syncthreads();

        #pragma unroll
        for (int ks = 0; ks < 2; ++ks) {
            s16x8 af[4], bf[4];
            #pragma unroll
            for (int i = 0; i < 4; ++i)
                af[i] = *(const s16x8*)(AsF + (size_t)(64 * wr + 16 * i + lanelo) * 64 + ks * 32 + quad * 8);
            #pragma unroll
            for (int j = 0; j < 4; ++j)
                bf[j] = *(const s16x8*)(BsF + (size_t)(64 * wc + 16 * j + lanelo) * 64 + ks * 32 + quad * 8);
            #pragma unroll
            for (int i = 0; i < 4; ++i)
                #pragma unroll
                for (int j = 0; j < 4; ++j)
                    acc[i][j] = mfma16(af[i], bf[j], acc[i][j]);
        }
    }

    #pragma unroll
    for (int j = 0; j < 4; ++j) {
        int c = col0 + 64 * wc + 16 * j + lanelo;
        float vb = bias[c];
        #pragma unroll
        for (int i = 0; i < 4; ++i)
            #pragma unroll
            for (int r = 0; r < 4; ++r) {
                int row = row0 + 64 * wr + 16 * i + 4 * quad + r;
                C[(size_t)row * 512 + c] = acc[i][j][r] + vb;
            }
    }
}

// ---------------------------------------------------------------------------
extern "C" void kernel_launch(void* const* d_in, const int* in_sizes, int n_in,
                              void* d_out, int out_size, void* d_ws, size_t ws_size,
                              hipStream_t stream) {
    const float* x       = (const float*)d_in[0];
    const float* pos_enc = (const float*)d_in[1];
    const float* Wq      = (const float*)d_in[2];
    const float* bq      = (const float*)d_in[3];
    const float* Wk      = (const float*)d_in[4];
    const float* bk      = (const float*)d_in[5];
    const float* Wv      = (const float*)d_in[6];
    const float* bv      = (const float*)d_in[7];
    const float* Wpos    = (const float*)d_in[8];
    const float* pbu     = (const float*)d_in[9];
    const float* pbv     = (const float*)d_in[10];
    const float* Wo      = (const float*)d_in[11];
    const float* bo      = (const float*)d_in[12];
    float* out = (float*)d_out;

    const size_t M  = 8 * T_SEQ;                 // 8192
    const size_t SZ = M * D_MODEL;               // 4,194,304

    char* ws = (char*)d_ws;
    ushort_t* xb   = (ushort_t*)ws;              ws += SZ * 2;
    ushort_t* posb = (ushort_t*)ws;              ws += (size_t)2048 * 512 * 2;
    ushort_t* Qu_b = (ushort_t*)ws;              ws += SZ * 2;
    ushort_t* Qv_b = (ushort_t*)ws;              ws += SZ * 2;
    ushort_t* K_b  = (ushort_t*)ws;              ws += SZ * 2;
    ushort_t* VT_b = (ushort_t*)ws;              ws += SZ * 2;
    ushort_t* P_b  = (ushort_t*)ws;              ws += (size_t)2048 * 512 * 2;
    ushort_t* WT   = (ushort_t*)ws;              ws += (size_t)5 * 512 * 512 * 2;
    ushort_t* AOb  = (ushort_t*)ws;              ws += SZ * 2;

    dim3 blk(256);

    hipLaunchKernelGGL(prep, dim3(2880), blk, 0, stream,
                       x, pos_enc, Wq, Wk, Wv, Wpos, Wo, xb, posb, WT);

    hipLaunchKernelGGL(gemm_qkvp, dim3(13, 64), blk, 0, stream,
                       xb, posb, WT, bq, bk, bv, pbu, pbv,
                       Qu_b, Qv_b, K_b, VT_b, P_b);

    hipLaunchKernelGGL(attn_mfma, dim3(16, 8, 8), blk, 0, stream,
                       Qu_b, Qv_b, K_b, VT_b, P_b, AOb);

    hipLaunchKernelGGL(gemm_out, dim3(4, 64), blk, 0, stream,
                       AOb, WT + (size_t)4 * 512 * 512, bo, out);
}

// Round 11
// 205.410 us; speedup vs baseline: 1.3624x; 1.1233x over previous
//
#include <hip/hip_runtime.h>
#include <hip/hip_bf16.h>

#define T_SEQ 1024
#define D_MODEL 512
#define N_HEADS 8
#define D_HEAD 64
// 0.125 (1/sqrt(64)) * log2(e): scores computed directly in exp2 domain
#define KSCALE 0.1803368801111244f

typedef unsigned short ushort_t;
typedef short s16x8 __attribute__((ext_vector_type(8)));
typedef float f32x4 __attribute__((ext_vector_type(4)));

__device__ inline f32x4 mfma16(s16x8 a, s16x8 b, f32x4 c) {
    return __builtin_amdgcn_mfma_f32_16x16x32_bf16(a, b, c, 0, 0, 0);
}

__device__ inline ushort_t f2bf(float f) {   // RTNE float->bf16
    union { float f; unsigned u; } v; v.f = f;
    unsigned r = v.u + 0x7FFFu + ((v.u >> 16) & 1u);
    return (ushort_t)(r >> 16);
}
__device__ inline float bf2f(short s) {
    union { unsigned u; float f; } t; t.u = ((unsigned)(unsigned short)s) << 16; return t.f;
}
__device__ inline void cvt4(const float4 f, ushort_t* t) {
    t[0] = f2bf(f.x); t[1] = f2bf(f.y); t[2] = f2bf(f.z); t[3] = f2bf(f.w);
}
__device__ inline s16x8 pack8(const ushort_t* t) {
    s16x8 r;
    #pragma unroll
    for (int e = 0; e < 8; ++e) r[e] = (short)t[e];
    return r;
}

// XOR-swizzled LDS index for 64-u16-wide buffers: 16B chunk ^= (row & 7).
// Frag reads (chunk = 4ks+quad, row%8 = lanelo%8) become bank-conflict-free.
__device__ inline int lidx(int row, int chunk) {
    return row * 64 + ((chunk ^ (row & 7)) << 3);
}

// HBM -> LDS direct DMA, 16 B per lane. lds ptr must be wave-uniform
// (HW writes base + lane*16); global ptr is per-lane.
__device__ inline void gl_lds16(const ushort_t* g, ushort_t* l) {
    __builtin_amdgcn_global_load_lds(
        (const __attribute__((address_space(1))) unsigned*)g,
        (__attribute__((address_space(3))) unsigned*)l, 16, 0, 0);
}

// ---------------------------------------------------------------------------
// prep: blocks [0,2560) cast x->xb + pos->posb (row 2047 zeroed);
//       blocks [2560,2880) transpose+cast the 5 weight matrices into WT.
// ---------------------------------------------------------------------------
__global__ __launch_bounds__(256) void prep(
    const float* __restrict__ x, const float* __restrict__ pos,
    const float* __restrict__ W0, const float* __restrict__ W1,
    const float* __restrict__ W2, const float* __restrict__ W3,
    const float* __restrict__ W4,
    ushort_t* __restrict__ xb, ushort_t* __restrict__ posb,
    ushort_t* __restrict__ WT)
{
    __shared__ float T[64][68];
    const int bx = blockIdx.x;
    const int tid = threadIdx.x;
    if (bx < 2560) {
        const size_t N1 = (size_t)8192 * 512;
        size_t e = ((size_t)bx * 256 + tid) * 8;
        ushort_t tmp[8];
        if (e < N1) {
            const float4* s = (const float4*)(x + e);
            cvt4(s[0], tmp); cvt4(s[1], tmp + 4);
            *(s16x8*)(xb + e) = pack8(tmp);
        } else {
            size_t e2 = e - N1;                 // < 2048*512
            int row = (int)(e2 >> 9);
            if (row < 2047) {
                const float4* s = (const float4*)(pos + e2);
                cvt4(s[0], tmp); cvt4(s[1], tmp + 4);
            } else {
                #pragma unroll
                for (int i = 0; i < 8; ++i) tmp[i] = 0;
            }
            *(s16x8*)(posb + e2) = pack8(tmp);
        }
    } else {
        const int bz = bx - 2560;               // 0..319
        const int z = bz >> 6;                  // 0..4
        const int rem = bz & 63;
        const int n0 = (rem & 7) * 64, k0 = (rem >> 3) * 64;
        const float* W = (z == 0) ? W0 : (z == 1) ? W1
                       : (z == 2) ? W2 : (z == 3) ? W3 : W4;
        const int rr = tid >> 2, cc = (tid & 3) * 16;

        const float* src = W + (size_t)(k0 + rr) * 512 + n0 + cc;
        *(float4*)&T[rr][cc + 0]  = *(const float4*)(src);
        *(float4*)&T[rr][cc + 4]  = *(const float4*)(src + 4);
        *(float4*)&T[rr][cc + 8]  = *(const float4*)(src + 8);
        *(float4*)&T[rr][cc + 12] = *(const float4*)(src + 12);
        __syncthreads();

        ushort_t tmp[16];
        #pragma unroll
        for (int e = 0; e < 16; ++e) tmp[e] = f2bf(T[cc + e][rr]);
        ushort_t* dst = WT + ((size_t)z * 512 + n0 + rr) * 512 + k0 + cc;
        *(s16x8*)dst       = pack8(tmp);
        *(s16x8*)(dst + 8) = pack8(tmp + 8);
    }
}

// ---------------------------------------------------------------------------
// Fused QKV + P GEMM, 128x128 tiles, 4 waves, K=512, global_load_lds staging
// (unpadded [128][64] LDS tiles; 8 chunks of 16B per row). Qv is NOT stored:
// attn reconstructs it from Qu + (pbv-pbu)*KSCALE (per-column constant).
// Grid (13, 64): bx<12 -> qkv (set=col0>>9); bx==12 -> P GEMM.
// ---------------------------------------------------------------------------
__global__ __launch_bounds__(256) void gemm_qkvp(
    const ushort_t* __restrict__ xb, const ushort_t* __restrict__ posb,
    const ushort_t* __restrict__ WT,
    const float* __restrict__ bq, const float* __restrict__ bk,
    const float* __restrict__ bv, const float* __restrict__ pbu,
    ushort_t* __restrict__ Qu, ushort_t* __restrict__ Ko,
    ushort_t* __restrict__ VoT, ushort_t* __restrict__ Po)
{
    const int tid = threadIdx.x;
    const bool is_p = (blockIdx.x == 12);
    int row0, col0;
    const ushort_t* A;
    const ushort_t* B;
    if (is_p) {
        row0 = ((int)blockIdx.y >> 2) * 128;     // 0..1920
        col0 = ((int)blockIdx.y & 3) * 128;      // 0..384
        A = posb;
        B = WT + (size_t)3 * 512 * 512;
    } else {
        row0 = blockIdx.y * 128;
        col0 = blockIdx.x * 128;
        A = xb;
        B = WT;                                  // col0 spans 0..1535 across sets
    }
    const int w = tid >> 6, lane = tid & 63;
    const int quad = lane >> 4, lanelo = lane & 15;
    const int wr = w >> 1, wc = w & 1;

    __shared__ ushort_t AsF[128 * 64];           // 16 KB, unpadded (DMA dest)
    __shared__ ushort_t BsF[128 * 64];           // 16 KB

    f32x4 acc[4][4] = {};

    for (int k0 = 0; k0 < 512; k0 += 64) {
        __syncthreads();
        #pragma unroll
        for (int i = 0; i < 4; ++i) {
            const int L = i * 256 + tid;         // 16B-chunk id, 0..1023
            const int r = L >> 3, j = (L & 7) * 8;   // 8 chunks per 64-ushort row
            ushort_t* lbase = AsF + (size_t)(i * 256 + (tid & ~63)) * 8;  // wave-uniform
            gl_lds16(A + (size_t)(row0 + r) * 512 + k0 + j, lbase);
            ushort_t* lbase2 = BsF + (size_t)(i * 256 + (tid & ~63)) * 8;
            gl_lds16(B + (size_t)(col0 + r) * 512 + k0 + j, lbase2);
        }
        __syncthreads();                         // drains vmcnt before barrier

        #pragma unroll
        for (int ks = 0; ks < 2; ++ks) {
            s16x8 af[4], bf[4];
            #pragma unroll
            for (int i = 0; i < 4; ++i)
                af[i] = *(const s16x8*)(AsF + (size_t)(64 * wr + 16 * i + lanelo) * 64 + ks * 32 + quad * 8);
            #pragma unroll
            for (int j = 0; j < 4; ++j)
                bf[j] = *(const s16x8*)(BsF + (size_t)(64 * wc + 16 * j + lanelo) * 64 + ks * 32 + quad * 8);
            #pragma unroll
            for (int i = 0; i < 4; ++i)
                #pragma unroll
                for (int j = 0; j < 4; ++j)
                    acc[i][j] = mfma16(af[i], bf[j], acc[i][j]);
        }
    }

    if (is_p) {
        #pragma unroll
        for (int j = 0; j < 4; ++j) {
            int c = col0 + 64 * wc + 16 * j + lanelo;
            #pragma unroll
            for (int i = 0; i < 4; ++i)
                #pragma unroll
                for (int r = 0; r < 4; ++r) {
                    int row = row0 + 64 * wr + 16 * i + 4 * quad + r;
                    Po[(size_t)row * 512 + c] = f2bf(acc[i][j][r]);
                }
        }
        return;
    }

    const int set = col0 >> 9;               // 0=Q,1=K,2=V (tile never straddles)
    const int cbase = (col0 & 511) + 64 * wc;
    if (set == 0) {
        #pragma unroll
        for (int j = 0; j < 4; ++j) {
            int c = cbase + 16 * j + lanelo;
            float vq = bq[c] + pbu[c];
            #pragma unroll
            for (int i = 0; i < 4; ++i)
                #pragma unroll
                for (int r = 0; r < 4; ++r) {
                    int row = row0 + 64 * wr + 16 * i + 4 * quad + r;
                    Qu[(size_t)row * 512 + c] = f2bf((acc[i][j][r] + vq) * KSCALE);
                }
        }
    } else if (set == 1) {
        #pragma unroll
        for (int j = 0; j < 4; ++j) {
            int c = cbase + 16 * j + lanelo;
            float vbk = bk[c];
            #pragma unroll
            for (int i = 0; i < 4; ++i)
                #pragma unroll
                for (int r = 0; r < 4; ++r) {
                    int row = row0 + 64 * wr + 16 * i + 4 * quad + r;
                    Ko[(size_t)row * 512 + c] = f2bf(acc[i][j][r] + vbk);
                }
        }
    } else {
        const int b_idx = row0 >> 10;
        #pragma unroll
        for (int j = 0; j < 4; ++j) {
            int c = cbase + 16 * j + lanelo;
            int hh = c >> 6, d = c & 63;
            float vbb = bv[c];
            #pragma unroll
            for (int i = 0; i < 4; ++i) {
                int t = (row0 & 1023) + 64 * wr + 16 * i + 4 * quad;
                ushort4 vp;
                vp.x = f2bf(acc[i][j][0] + vbb);
                vp.y = f2bf(acc[i][j][1] + vbb);
                vp.z = f2bf(acc[i][j][2] + vbb);
                vp.w = f2bf(acc[i][j][3] + vbb);
                *(ushort4*)(VoT + ((size_t)((b_idx * 8 + hh) * 64 + d)) * 1024 + t) = vp;
            }
        }
    }
}

// ---------------------------------------------------------------------------
// MFMA flash attention. XOR-swizzled unpadded LDS (40960 B total = 4 blocks/CU,
// conflict-free MFMA frag reads). Qv reconstructed in-register from
// Qu + (pbv-pbu)*KSCALE. No private indexed arrays in hot loop (PromoteAlloca).
// Fused relative shift (banded shuffle extraction), no-max exp2 softmax,
// circular 128-slot P window, register-prefetch pipeline.
// Block: (64 q-rows, h, b); wave w owns rows [16w,16w+16).
// ---------------------------------------------------------------------------
__global__ __launch_bounds__(256) void attn_mfma(
    const ushort_t* __restrict__ Qu,
    const ushort_t* __restrict__ Kb, const ushort_t* __restrict__ VT,
    const ushort_t* __restrict__ Pb,
    const float* __restrict__ pbu, const float* __restrict__ pbv,
    ushort_t* __restrict__ AOb)
{
    const int tid = threadIdx.x;
    const int t0 = blockIdx.x * 64;
    const int h  = blockIdx.y;
    const int b  = blockIdx.z;
    const int w = tid >> 6, lane = tid & 63;
    const int quad = lane >> 4, lanelo = lane & 15;
    const int sr = tid >> 2;                 // 0..63
    const int scch = (tid & 3) * 2;          // chunk pair base for staging
    const int sc = scch * 8;                 // u16 col base

    __shared__ ushort_t Kt[64 * 64];     //  8192 B  [s][d] swizzled
    __shared__ ushort_t VtT[64 * 64];    //  8192 B  [d][s] swizzled
    __shared__ ushort_t Pt[128 * 64];    // 16384 B  circular, slot = row & 127
    __shared__ ushort_t Ps[64 * 64];     //  8192 B  probs / O staging -> 40960 B

    const size_t qrow = (size_t)(b * T_SEQ + t0 + 16 * w + lanelo) * 512 + h * 64;
    s16x8 qu[2], qv[2];
    qu[0] = *(const s16x8*)(Qu + qrow + quad * 8);
    qu[1] = *(const s16x8*)(Qu + qrow + 32 + quad * 8);
    // qv = qu + (pbv - pbu)*KSCALE  (per-k constant; k = ks*32 + quad*8 + e)
    #pragma unroll
    for (int e = 0; e < 8; ++e) {
        int k0i = h * 64 + quad * 8 + e;
        float d0 = (pbv[k0i] - pbu[k0i]) * KSCALE;
        float d1 = (pbv[k0i + 32] - pbu[k0i + 32]) * KSCALE;
        qv[0][e] = (short)f2bf(bf2f(qu[0][e]) + d0);
        qv[1][e] = (short)f2bf(bf2f(qu[1][e]) + d1);
    }

    f32x4 acc_o[4] = {};
    float l_part[4] = {0.f, 0.f, 0.f, 0.f};

    const int u_base = lanelo + 63 - 4 * quad;       // u = u_base - r in [48,78]
    const ushort_t* VTbh = VT + ((size_t)((b * 8 + h) * 64)) * 1024;
    const ushort_t* Kbh  = Kb + (size_t)b * T_SEQ * 512 + (size_t)h * 64;
    const int pr_base = 960 - t0;                    // window start at s0=0

    // ---- prologue: stage iter-0 K, V^T, and full 128-row P window ----
    {
        const ushort_t* kp = Kbh + (size_t)sr * 512 + sc;
        *(s16x8*)(Kt + lidx(sr, scch))     = *(const s16x8*)kp;
        *(s16x8*)(Kt + lidx(sr, scch + 1)) = *(const s16x8*)(kp + 8);
        const ushort_t* vp = VTbh + (size_t)sr * 1024 + sc;
        *(s16x8*)(VtT + lidx(sr, scch))     = *(const s16x8*)vp;
        *(s16x8*)(VtT + lidx(sr, scch + 1)) = *(const s16x8*)(vp + 8);
        const int pr_r = tid >> 1, pc0 = (tid & 1) * 4;
        const int slot = (pr_base + pr_r) & 127;
        const ushort_t* gp = Pb + (size_t)(pr_base + pr_r) * 512 + h * 64 + pc0 * 8;
        *(s16x8*)(Pt + lidx(slot, pc0))     = *(const s16x8*)(gp +  0);
        *(s16x8*)(Pt + lidx(slot, pc0 + 1)) = *(const s16x8*)(gp +  8);
        *(s16x8*)(Pt + lidx(slot, pc0 + 2)) = *(const s16x8*)(gp + 16);
        *(s16x8*)(Pt + lidx(slot, pc0 + 3)) = *(const s16x8*)(gp + 24);
    }

    for (int it = 0; it < 16; ++it) {
        const int s0 = it * 64;
        __syncthreads();                 // staged data visible

        // ---- prefetch next iter into registers (VMEM overlaps compute) ----
        s16x8 kp0, kp1, vp0, vp1, pp0, pp1;
        const bool more = (it < 15);
        if (more) {
            const ushort_t* kp = Kbh + (size_t)(s0 + 64 + sr) * 512 + sc;
            kp0 = *(const s16x8*)kp;
            kp1 = *(const s16x8*)(kp + 8);
            const ushort_t* vp = VTbh + (size_t)sr * 1024 + s0 + 64 + sc;
            vp0 = *(const s16x8*)vp;
            vp1 = *(const s16x8*)(vp + 8);
            const ushort_t* gp = Pb + (size_t)(pr_base + s0 + 128 + sr) * 512 + h * 64 + sc;
            pp0 = *(const s16x8*)gp;
            pp1 = *(const s16x8*)(gp + 8);
        }

        // ---- compute ----
        const int pbase = (pr_base + s0) & 127;
        f32x4 acc_c[4] = {};
        f32x4 acc_g[5] = {};
        #pragma unroll
        for (int ks = 0; ks < 2; ++ks) {
            #pragma unroll
            for (int tn = 0; tn < 4; ++tn) {
                s16x8 kf = *(const s16x8*)(Kt + lidx(tn * 16 + lanelo, 4 * ks + quad));
                acc_c[tn] = mfma16(qu[ks], kf, acc_c[tn]);
            }
            #pragma unroll
            for (int i = 0; i < 5; ++i) {      // jt = 3 - w + i
                int prow = (pbase + (3 - w + i) * 16 + lanelo) & 127;
                s16x8 pf = *(const s16x8*)(Pt + lidx(prow, 4 * ks + quad));
                acc_g[i] = mfma16(qv[ks], pf, acc_g[i]);
            }
        }

        // band extraction + exp2 (no max subtraction; softmax shift-invariant)
        float p[4][4];
        #pragma unroll
        for (int r = 0; r < 4; ++r) {
            int u = u_base - r;
            int srcl = (quad << 4) | (u & 15);
            bool hi = (u >= 64);
            #pragma unroll
            for (int tn = 0; tn < 4; ++tn) {
                float v0 = __shfl(acc_g[tn][r], srcl);
                float v1 = __shfl(acc_g[tn + 1][r], srcl);
                float e = __builtin_amdgcn_exp2f(acc_c[tn][r] + (hi ? v1 : v0));
                p[tn][r] = e;
                l_part[r] += e;
            }
        }
        #pragma unroll
        for (int tn = 0; tn < 4; ++tn)
            #pragma unroll
            for (int r = 0; r < 4; ++r) {
                int pr = 16 * w + 4 * quad + r;
                int ch = 2 * tn + (lanelo >> 3);
                Ps[pr * 64 + ((ch ^ (pr & 7)) << 3) + (lanelo & 7)] = f2bf(p[tn][r]);
            }
        asm volatile("s_waitcnt lgkmcnt(0)" ::: "memory");

        // PV: A = probs (wave-private Ps rows), B = V^T tile in LDS
        #pragma unroll
        for (int ks = 0; ks < 2; ++ks) {
            s16x8 af = *(const s16x8*)(Ps + lidx(16 * w + lanelo, 4 * ks + quad));
            #pragma unroll
            for (int dt = 0; dt < 4; ++dt) {
                s16x8 vb = *(const s16x8*)(VtT + lidx(dt * 16 + lanelo, 4 * ks + quad));
                acc_o[dt] = mfma16(af, vb, acc_o[dt]);
            }
        }

        __syncthreads();                 // compute done before LDS overwrite
        if (more) {
            *(s16x8*)(Kt + lidx(sr, scch))      = kp0;
            *(s16x8*)(Kt + lidx(sr, scch + 1))  = kp1;
            *(s16x8*)(VtT + lidx(sr, scch))     = vp0;
            *(s16x8*)(VtT + lidx(sr, scch + 1)) = vp1;
            const int slot = (pr_base + s0 + 128 + sr) & 127;
            *(s16x8*)(Pt + lidx(slot, scch))     = pp0;
            *(s16x8*)(Pt + lidx(slot, scch + 1)) = pp1;
        }
    }

    // single end-of-kernel l reduction (16 lanes per row group)
    float inv[4];
    #pragma unroll
    for (int r = 0; r < 4; ++r) {
        float l = l_part[r];
        l += __shfl_xor(l, 1);
        l += __shfl_xor(l, 2);
        l += __shfl_xor(l, 4);
        l += __shfl_xor(l, 8);
        inv[r] = 1.0f / l;
    }

    // epilogue: stage O into Ps (bf16, swizzled), then coalesced vector stores
    __syncthreads();
    #pragma unroll
    for (int r = 0; r < 4; ++r)
        #pragma unroll
        for (int dt = 0; dt < 4; ++dt) {
            int pr = 16 * w + 4 * quad + r;
            int ch = 2 * dt + (lanelo >> 3);
            Ps[pr * 64 + ((ch ^ (pr & 7)) << 3) + (lanelo & 7)] = f2bf(acc_o[dt][r] * inv[r]);
        }
    __syncthreads();
    {
        ushort_t* dst = AOb + (size_t)(b * T_SEQ + t0 + sr) * 512 + h * 64 + sc;
        *(s16x8*)dst       = *(const s16x8*)(Ps + lidx(sr, scch));
        *(s16x8*)(dst + 8) = *(const s16x8*)(Ps + lidx(sr, scch + 1));
    }
}

// ---------------------------------------------------------------------------
// Final projection: out = AOb @ WoT + bo  (A bf16, fp32 out), 128x128 tiles,
// global_load_lds staging.
// ---------------------------------------------------------------------------
__global__ __launch_bounds__(256) void gemm_out(
    const ushort_t* __restrict__ A, const ushort_t* __restrict__ WTo,
    const float* __restrict__ bias, float* __restrict__ C)
{
    const int tid = threadIdx.x;
    const int col0 = blockIdx.x * 128;
    const int row0 = blockIdx.y * 128;
    const int w = tid >> 6, lane = tid & 63;
    const int quad = lane >> 4, lanelo = lane & 15;
    const int wr = w >> 1, wc = w & 1;

    __shared__ ushort_t AsF[128 * 64];
    __shared__ ushort_t BsF[128 * 64];

    f32x4 acc[4][4] = {};

    for (int k0 = 0; k0 < 512; k0 += 64) {
        __syncthreads();
        #pragma unroll
        for (int i = 0; i < 4; ++i) {
            const int L = i * 256 + tid;
            const int r = L >> 3, j = (L & 7) * 8;   // 8 chunks per 64-ushort row
            ushort_t* lbase = AsF + (size_t)(i * 256 + (tid & ~63)) * 8;
            gl_lds16(A + (size_t)(row0 + r) * 512 + k0 + j, lbase);
            ushort_t* lbase2 = BsF + (size_t)(i * 256 + (tid & ~63)) * 8;
            gl_lds16(WTo + (size_t)(col0 + r) * 512 + k0 + j, lbase2);
        }
        __syncthreads();

        #pragma unroll
        for (int ks = 0; ks < 2; ++ks) {
            s16x8 af[4], bf[4];
            #pragma unroll
            for (int i = 0; i < 4; ++i)
                af[i] = *(const s16x8*)(AsF + (size_t)(64 * wr + 16 * i + lanelo) * 64 + ks * 32 + quad * 8);
            #pragma unroll
            for (int j = 0; j < 4; ++j)
                bf[j] = *(const s16x8*)(BsF + (size_t)(64 * wc + 16 * j + lanelo) * 64 + ks * 32 + quad * 8);
            #pragma unroll
            for (int i = 0; i < 4; ++i)
                #pragma unroll
                for (int j = 0; j < 4; ++j)
                    acc[i][j] = mfma16(af[i], bf[j], acc[i][j]);
        }
    }

    #pragma unroll
    for (int j = 0; j < 4; ++j) {
        int c = col0 + 64 * wc + 16 * j + lanelo;
        float vb = bias[c];
        #pragma unroll
        for (int i = 0; i < 4; ++i)
            #pragma unroll
            for (int r = 0; r < 4; ++r) {
                int row = row0 + 64 * wr + 16 * i + 4 * quad + r;
                C[(size_t)row * 512 + c] = acc[i][j][r] + vb;
            }
    }
}

// ---------------------------------------------------------------------------
extern "C" void kernel_launch(void* const* d_in, const int* in_sizes, int n_in,
                              void* d_out, int out_size, void* d_ws, size_t ws_size,
                              hipStream_t stream) {
    const float* x       = (const float*)d_in[0];
    const float* pos_enc = (const float*)d_in[1];
    const float* Wq      = (const float*)d_in[2];
    const float* bq      = (const float*)d_in[3];
    const float* Wk      = (const float*)d_in[4];
    const float* bk      = (const float*)d_in[5];
    const float* Wv      = (const float*)d_in[6];
    const float* bv      = (const float*)d_in[7];
    const float* Wpos    = (const float*)d_in[8];
    const float* pbu     = (const float*)d_in[9];
    const float* pbv     = (const float*)d_in[10];
    const float* Wo      = (const float*)d_in[11];
    const float* bo      = (const float*)d_in[12];
    float* out = (float*)d_out;

    const size_t M  = 8 * T_SEQ;                 // 8192
    const size_t SZ = M * D_MODEL;               // 4,194,304

    char* ws = (char*)d_ws;
    ushort_t* xb   = (ushort_t*)ws;              ws += SZ * 2;
    ushort_t* posb = (ushort_t*)ws;              ws += (size_t)2048 * 512 * 2;
    ushort_t* Qu_b = (ushort_t*)ws;              ws += SZ * 2;
    ushort_t* K_b  = (ushort_t*)ws;              ws += SZ * 2;
    ushort_t* VT_b = (ushort_t*)ws;              ws += SZ * 2;
    ushort_t* P_b  = (ushort_t*)ws;              ws += (size_t)2048 * 512 * 2;
    ushort_t* WT   = (ushort_t*)ws;              ws += (size_t)5 * 512 * 512 * 2;
    ushort_t* AOb  = (ushort_t*)ws;              ws += SZ * 2;

    dim3 blk(256);

    hipLaunchKernelGGL(prep, dim3(2880), blk, 0, stream,
                       x, pos_enc, Wq, Wk, Wv, Wpos, Wo, xb, posb, WT);

    hipLaunchKernelGGL(gemm_qkvp, dim3(13, 64), blk, 0, stream,
                       xb, posb, WT, bq, bk, bv, pbu,
                       Qu_b, K_b, VT_b, P_b);

    hipLaunchKernelGGL(attn_mfma, dim3(16, 8, 8), blk, 0, stream,
                       Qu_b, K_b, VT_b, P_b, pbu, pbv, AOb);

    hipLaunchKernelGGL(gemm_out, dim3(4, 64), blk, 0, stream,
                       AOb, WT + (size_t)4 * 512 * 512, bo, out);
}